// Round 10
// baseline (4190.184 us; speedup 1.0000x reference)
//
#include <hip/hip_runtime.h>

#define TSTEPS 2000
#define NBATCH 16
#define DDIM   512
#define HDIM   512
#define MTOT   (NBATCH * TSTEPS)
#define LEPS   1e-5f

typedef _Float16 f16x8 __attribute__((ext_vector_type(8)));
typedef _Float16 f16x4 __attribute__((ext_vector_type(4)));
typedef float    f32x4 __attribute__((ext_vector_type(4)));
typedef unsigned long long u64;

// ---------------- Phase 1: w = BN(x @ W^T), f16 MFMA ----------------  (r4, verified ~60us)
__global__ __launch_bounds__(256) void gemm_bn_f16_kernel(
    const float* __restrict__ x, const float* __restrict__ W,
    const float* __restrict__ gamma, const float* __restrict__ beta,
    const float* __restrict__ rmean, const float* __restrict__ rvar,
    float* __restrict__ out_a, float* __restrict__ out_z)
{
  __shared__ _Float16 Asm[128 * 64];
  __shared__ _Float16 Bsm[128 * 64];
  const int tid  = threadIdx.x;
  const int wv   = tid >> 6;
  const int lane = tid & 63;
  const int c    = lane & 15;
  const int hi   = lane >> 4;
  const int m0   = blockIdx.x * 128;
  const int n0   = blockIdx.y * 128;

  float invg[2], mng[2], btg[2];
#pragma unroll
  for (int nt = 0; nt < 2; ++nt) {
    const int gc = n0 + wv * 32 + nt * 16 + c;
    invg[nt] = gamma[gc] * rsqrtf(rvar[gc] + LEPS);
    mng[nt]  = rmean[gc];
    btg[nt]  = beta[gc];
  }

  f32x4 acc[8][2];
#pragma unroll
  for (int mt = 0; mt < 8; ++mt)
#pragma unroll
    for (int nt = 0; nt < 2; ++nt) acc[mt][nt] = (f32x4){0.f, 0.f, 0.f, 0.f};

  const int sf4  = tid & 15;
  const int srow = tid >> 4;

  for (int k0 = 0; k0 < DDIM; k0 += 64) {
    __syncthreads();
#pragma unroll
    for (int p = 0; p < 8; ++p) {
      const int r = p * 16 + srow;
      float4 va = *(const float4*)&x[(size_t)(m0 + r) * DDIM + k0 + sf4 * 4];
      float4 vb = *(const float4*)&W[(size_t)(n0 + r) * DDIM + k0 + sf4 * 4];
      f16x4 ha, hb;
      ha[0] = (_Float16)va.x; ha[1] = (_Float16)va.y;
      ha[2] = (_Float16)va.z; ha[3] = (_Float16)va.w;
      hb[0] = (_Float16)vb.x; hb[1] = (_Float16)vb.y;
      hb[2] = (_Float16)vb.z; hb[3] = (_Float16)vb.w;
      const int byo = r * 128 + ((sf4 * 8) ^ ((r & 7) << 4));
      *(f16x4*)((char*)Asm + byo) = ha;
      *(f16x4*)((char*)Bsm + byo) = hb;
    }
    __syncthreads();
#pragma unroll
    for (int kc = 0; kc < 2; ++kc) {
      const int kof = (kc * 32 + hi * 8) * 2;
      f16x8 bfr[2];
#pragma unroll
      for (int nt = 0; nt < 2; ++nt) {
        const int rr = wv * 32 + nt * 16 + c;
        bfr[nt] = *(const f16x8*)((const char*)Bsm + rr * 128 + (kof ^ ((rr & 7) << 4)));
      }
#pragma unroll
      for (int mt = 0; mt < 8; ++mt) {
        const int rr = mt * 16 + c;
        f16x8 afr = *(const f16x8*)((const char*)Asm + rr * 128 + (kof ^ ((rr & 7) << 4)));
        acc[mt][0] = __builtin_amdgcn_mfma_f32_16x16x32_f16(afr, bfr[0], acc[mt][0], 0, 0, 0);
        acc[mt][1] = __builtin_amdgcn_mfma_f32_16x16x32_f16(afr, bfr[1], acc[mt][1], 0, 0, 0);
      }
    }
  }

  const bool isA = (n0 < HDIM);
  float* dst = isA ? out_a : out_z;
  const int cb = isA ? n0 : (n0 - HDIM);
#pragma unroll
  for (int mt = 0; mt < 8; ++mt)
#pragma unroll
    for (int nt = 0; nt < 2; ++nt) {
      const int col = cb + wv * 32 + nt * 16 + c;
#pragma unroll
      for (int i = 0; i < 4; ++i) {
        const int row = m0 + mt * 16 + hi * 4 + i;
        dst[(size_t)row * HDIM + col] = (acc[mt][nt][i] - mng[nt]) * invg[nt] + btg[nt];
      }
    }
}

// ---------------- Phase 2: 4-batch-interleaved clusters, M=4 MFMA ----------------
// 32 blocks = 4 clusters (q=bid&3) x 8 groups (g=bid>>2). Cluster q owns batches
// {q, q+4, q+8, q+12}; block (q,g) publishes cols [g0,g0+64) for all 4 batches.
// Key idea: the exchange RT (~2000cy) hides under the OTHER batches' compute,
// and the MFMA M-dim carries 4 batches at once (A rows 0-3 = batches; A-frag
// row = lane&15, k = (lane>>4)*8+j -- mirror of the B layout verified r3-r9).
// Per iteration t (advances ALL 4 batches one step):
//   A: spin 4 {tag,f32 h} atoms (own col, one per batch; published ~1 iter ago
//      so usually already visible); 4x ds_write f16 -> hbuf[bat][t&1].
//   bar (only barrier).
//   B: 16 ds_read_b128 (lane reads batch row c&3) + 16 MFMAs in 4 indep chains;
//      accS = sum -> accS[i] = batch-i dot for this lane's U row; shfl_xor(8)
//      pairs a/z rows (r5 in-wave mapping); publisher lanes (hi==0,c<8) do 4x
//      gate math + 4 tagged publishes + 4 out stores.
//   D: hidden tail: ring w write (slot t+3, carried) + issue w[t+4] load.
// Protocol per batch identical to r3 (equality spin, parity slots); cross-batch
// deadlock-free by induction: publish(*,t+1) follows bar which follows ALL 4
// batches' spins(t), and cluster blocks are the only publishers of their cols.
__global__ __launch_bounds__(512, 2) void rnn_mb_kernel(
    const float* __restrict__ U,
    float* __restrict__ out,              // [16][2000][512]: w_a in, h out (in place)
    const float* __restrict__ wz,         // [16][2000][512]
    u64* __restrict__ xbuf)               // [2][4][4][512] {tag,f32} -- memset 0/launch
{
  __shared__ __align__(16) _Float16 hbuf[4][2][528];  // [bat][par][col], 528 de-banks bats
  __shared__ float ring[4][4][2][64];                 // [slot][bat][a|z][col64]

  const int tid  = threadIdx.x;
  const int w    = tid >> 6;
  const int lane = tid & 63;
  const int c    = lane & 15;
  const int hi   = lane >> 4;
  const int bid  = blockIdx.x;
  const int q    = bid & 3, g = bid >> 2;
  const int g0   = g * 64;

  // persistent U B-fragments (r5 in-wave a/z mapping): wave w, col j=w*8+(c&7)
  const int urow = (c < 8) ? (g0 + w * 8 + c) : (HDIM + g0 + w * 8 + (c - 8));
  f16x8 ufrag[16];
  {
    const float* up = &U[(size_t)urow * HDIM + hi * 8];
#pragma unroll
    for (int kt = 0; kt < 16; ++kt) {
      float4 lo = *(const float4*)&up[kt * 32];
      float4 h4 = *(const float4*)&up[kt * 32 + 4];
      f16x8 f;
      f[0] = (_Float16)lo.x; f[1] = (_Float16)lo.y;
      f[2] = (_Float16)lo.z; f[3] = (_Float16)lo.w;
      f[4] = (_Float16)h4.x; f[5] = (_Float16)h4.y;
      f[6] = (_Float16)h4.z; f[7] = (_Float16)h4.w;
      ufrag[kt] = f;
    }
  }

#pragma unroll
  for (int i = 0; i < 4; ++i) {
    hbuf[i][0][tid] = (_Float16)0.f;
    hbuf[i][1][tid] = (_Float16)0.f;
  }

  // ring prefill: thread -> (bat i_pf, a|z, col idx); one 4B load per step
  const int i_pf = tid >> 7;
  const int az   = (tid >> 6) & 1;
  const int idx  = tid & 63;
  const float* wsrc = az ? wz : out;
  const size_t opf  = (size_t)(q + 4 * i_pf) * TSTEPS * HDIM + g0 + idx;
#pragma unroll
  for (int p = 0; p < 3; ++p) ring[p][i_pf][az][idx] = wsrc[opf + (size_t)p * HDIM];
  float pv = wsrc[opf + (size_t)3 * HDIM];

  const bool ispub = (hi == 0) && (c < 8);
  const int  jloc  = w * 8 + c;               // published col-local (valid c<8)
  float hold[4] = {0.f, 0.f, 0.f, 0.f};       // h[bat][own col], register-carried
  __syncthreads();

  for (int t = 0; t < TSTEPS; ++t) {
    const int par = t & 1;
    // ---- A: spin 4 atoms (parallel poll), 4 hbuf writes ----
    if (t > 0) {
      const unsigned want = (unsigned)t;
      u64* xp = xbuf + ((size_t)(par * 4 + q) * 4) * 512 + tid;
      u64 v0 = __hip_atomic_load(xp,        __ATOMIC_RELAXED, __HIP_MEMORY_SCOPE_AGENT);
      u64 v1 = __hip_atomic_load(xp + 512,  __ATOMIC_RELAXED, __HIP_MEMORY_SCOPE_AGENT);
      u64 v2 = __hip_atomic_load(xp + 1024, __ATOMIC_RELAXED, __HIP_MEMORY_SCOPE_AGENT);
      u64 v3 = __hip_atomic_load(xp + 1536, __ATOMIC_RELAXED, __HIP_MEMORY_SCOPE_AGENT);
      for (;;) {
        const bool k0 = (unsigned)(v0 >> 32) == want;
        const bool k1 = (unsigned)(v1 >> 32) == want;
        const bool k2 = (unsigned)(v2 >> 32) == want;
        const bool k3 = (unsigned)(v3 >> 32) == want;
        if (k0 && k1 && k2 && k3) break;
        if (!k0) v0 = __hip_atomic_load(xp,        __ATOMIC_RELAXED, __HIP_MEMORY_SCOPE_AGENT);
        if (!k1) v1 = __hip_atomic_load(xp + 512,  __ATOMIC_RELAXED, __HIP_MEMORY_SCOPE_AGENT);
        if (!k2) v2 = __hip_atomic_load(xp + 1024, __ATOMIC_RELAXED, __HIP_MEMORY_SCOPE_AGENT);
        if (!k3) v3 = __hip_atomic_load(xp + 1536, __ATOMIC_RELAXED, __HIP_MEMORY_SCOPE_AGENT);
      }
      hbuf[0][par][tid] = (_Float16)__uint_as_float((unsigned)v0);
      hbuf[1][par][tid] = (_Float16)__uint_as_float((unsigned)v1);
      hbuf[2][par][tid] = (_Float16)__uint_as_float((unsigned)v2);
      hbuf[3][par][tid] = (_Float16)__uint_as_float((unsigned)v3);
    }
    __syncthreads();                           // the only barrier

    // ---- B: M=4 MFMA (A rows = batches; lane reads batch row c&3) ----
    const _Float16* hbA = hbuf[c & 3][par];
    f32x4 acc0 = {0.f, 0.f, 0.f, 0.f};
    f32x4 acc1 = {0.f, 0.f, 0.f, 0.f};
    f32x4 acc2 = {0.f, 0.f, 0.f, 0.f};
    f32x4 acc3 = {0.f, 0.f, 0.f, 0.f};
#pragma unroll
    for (int q4 = 0; q4 < 4; ++q4) {
      f16x8 a0 = *(const f16x8*)&hbA[(q4 * 4 + 0) * 32 + hi * 8];
      f16x8 a1 = *(const f16x8*)&hbA[(q4 * 4 + 1) * 32 + hi * 8];
      f16x8 a2 = *(const f16x8*)&hbA[(q4 * 4 + 2) * 32 + hi * 8];
      f16x8 a3 = *(const f16x8*)&hbA[(q4 * 4 + 3) * 32 + hi * 8];
      acc0 = __builtin_amdgcn_mfma_f32_16x16x32_f16(a0, ufrag[q4 * 4 + 0], acc0, 0, 0, 0);
      acc1 = __builtin_amdgcn_mfma_f32_16x16x32_f16(a1, ufrag[q4 * 4 + 1], acc1, 0, 0, 0);
      acc2 = __builtin_amdgcn_mfma_f32_16x16x32_f16(a2, ufrag[q4 * 4 + 2], acc2, 0, 0, 0);
      acc3 = __builtin_amdgcn_mfma_f32_16x16x32_f16(a3, ufrag[q4 * 4 + 3], acc3, 0, 0, 0);
    }
    // accS[i] = batch-i dot of this lane's U row (valid for hi==0 lanes)
    const f32x4 accS = (acc0 + acc1) + (acc2 + acc3);
    const float peer0 = __shfl_xor(accS[0], 8);   // paired a<->z row, batch 0
    const float peer1 = __shfl_xor(accS[1], 8);
    const float peer2 = __shfl_xor(accS[2], 8);
    const float peer3 = __shfl_xor(accS[3], 8);

    if (ispub) {
      const float ownv[4]  = {accS[0], accS[1], accS[2], accS[3]};
      const float peerv[4] = {peer0, peer1, peer2, peer3};
#pragma unroll
      for (int i = 0; i < 4; ++i) {
        const float a_pre = ownv[i]  + ring[t & 3][i][0][jloc];
        const float zg    = peerv[i] + ring[t & 3][i][1][jloc];
        const float z  = 1.f / (1.f + __expf(-zg));
        const float hc = fmaxf(a_pre, 0.f);
        const float hn = z * hold[i] + (1.f - z) * hc;
        hold[i] = hn;
        if (t + 1 < TSTEPS) {
          const u64 pkt = ((u64)(unsigned)(t + 1) << 32) | (u64)__float_as_uint(hn);
          __hip_atomic_store(
              xbuf + ((size_t)(((t + 1) & 1) * 4 + q) * 4 + i) * 512 + g0 + jloc,
              pkt, __ATOMIC_RELAXED, __HIP_MEMORY_SCOPE_AGENT);
        }
        out[(size_t)(q + 4 * i) * TSTEPS * HDIM + (size_t)t * HDIM + g0 + jloc] = hn;
      }
    }

    // ---- D: hidden tail: ring write (carried) + issue next w load ----
    if (t + 3 < TSTEPS) ring[(t + 3) & 3][i_pf][az][idx] = pv;
    if (t + 4 < TSTEPS) pv = wsrc[opf + (size_t)(t + 4) * HDIM];
  }
}

extern "C" void kernel_launch(void* const* d_in, const int* in_sizes, int n_in,
                              void* d_out, int out_size, void* d_ws, size_t ws_size,
                              hipStream_t stream) {
  const float* x     = (const float*)d_in[0];
  const float* W     = (const float*)d_in[1];
  const float* U     = (const float*)d_in[2];
  const float* gamma = (const float*)d_in[3];
  const float* beta  = (const float*)d_in[4];
  const float* rmean = (const float*)d_in[5];
  const float* rvar  = (const float*)d_in[6];
  float* out = (float*)d_out;

  const size_t wz_bytes = (size_t)MTOT * HDIM * sizeof(float);   // 65,536,000
  float* wzp = (float*)d_ws;
  u64*  xbuf = (u64*)((char*)d_ws + wz_bytes);                   // [2][4][4][512] u64

  hipMemsetAsync(xbuf, 0, (size_t)2 * 4 * 4 * 512 * sizeof(u64), stream);

  dim3 g1(MTOT / 128, (HDIM * 2) / 128), b1(256);
  gemm_bn_f16_kernel<<<g1, b1, 0, stream>>>(x, W, gamma, beta, rmean, rvar, out, wzp);
  rnn_mb_kernel<<<dim3(32), dim3(512), 0, stream>>>(U, out, wzp, xbuf);
}

// Round 11
// 2906.455 us; speedup vs baseline: 1.4417x; 1.4417x over previous
//
#include <hip/hip_runtime.h>

#define TSTEPS 2000
#define NBATCH 16
#define DDIM   512
#define HDIM   512
#define MTOT   (NBATCH * TSTEPS)
#define LEPS   1e-5f

typedef _Float16 f16x8 __attribute__((ext_vector_type(8)));
typedef _Float16 f16x4 __attribute__((ext_vector_type(4)));
typedef float    f32x4 __attribute__((ext_vector_type(4)));
typedef unsigned long long u64;

// ---------------- Phase 1: w = BN(x @ W^T), f16 MFMA ----------------  (r4, verified ~60us)
__global__ __launch_bounds__(256) void gemm_bn_f16_kernel(
    const float* __restrict__ x, const float* __restrict__ W,
    const float* __restrict__ gamma, const float* __restrict__ beta,
    const float* __restrict__ rmean, const float* __restrict__ rvar,
    float* __restrict__ out_a, float* __restrict__ out_z)
{
  __shared__ _Float16 Asm[128 * 64];
  __shared__ _Float16 Bsm[128 * 64];
  const int tid  = threadIdx.x;
  const int wv   = tid >> 6;
  const int lane = tid & 63;
  const int c    = lane & 15;
  const int hi   = lane >> 4;
  const int m0   = blockIdx.x * 128;
  const int n0   = blockIdx.y * 128;

  float invg[2], mng[2], btg[2];
#pragma unroll
  for (int nt = 0; nt < 2; ++nt) {
    const int gc = n0 + wv * 32 + nt * 16 + c;
    invg[nt] = gamma[gc] * rsqrtf(rvar[gc] + LEPS);
    mng[nt]  = rmean[gc];
    btg[nt]  = beta[gc];
  }

  f32x4 acc[8][2];
#pragma unroll
  for (int mt = 0; mt < 8; ++mt)
#pragma unroll
    for (int nt = 0; nt < 2; ++nt) acc[mt][nt] = (f32x4){0.f, 0.f, 0.f, 0.f};

  const int sf4  = tid & 15;
  const int srow = tid >> 4;

  for (int k0 = 0; k0 < DDIM; k0 += 64) {
    __syncthreads();
#pragma unroll
    for (int p = 0; p < 8; ++p) {
      const int r = p * 16 + srow;
      float4 va = *(const float4*)&x[(size_t)(m0 + r) * DDIM + k0 + sf4 * 4];
      float4 vb = *(const float4*)&W[(size_t)(n0 + r) * DDIM + k0 + sf4 * 4];
      f16x4 ha, hb;
      ha[0] = (_Float16)va.x; ha[1] = (_Float16)va.y;
      ha[2] = (_Float16)va.z; ha[3] = (_Float16)va.w;
      hb[0] = (_Float16)vb.x; hb[1] = (_Float16)vb.y;
      hb[2] = (_Float16)vb.z; hb[3] = (_Float16)vb.w;
      const int byo = r * 128 + ((sf4 * 8) ^ ((r & 7) << 4));
      *(f16x4*)((char*)Asm + byo) = ha;
      *(f16x4*)((char*)Bsm + byo) = hb;
    }
    __syncthreads();
#pragma unroll
    for (int kc = 0; kc < 2; ++kc) {
      const int kof = (kc * 32 + hi * 8) * 2;
      f16x8 bfr[2];
#pragma unroll
      for (int nt = 0; nt < 2; ++nt) {
        const int rr = wv * 32 + nt * 16 + c;
        bfr[nt] = *(const f16x8*)((const char*)Bsm + rr * 128 + (kof ^ ((rr & 7) << 4)));
      }
#pragma unroll
      for (int mt = 0; mt < 8; ++mt) {
        const int rr = mt * 16 + c;
        f16x8 afr = *(const f16x8*)((const char*)Asm + rr * 128 + (kof ^ ((rr & 7) << 4)));
        acc[mt][0] = __builtin_amdgcn_mfma_f32_16x16x32_f16(afr, bfr[0], acc[mt][0], 0, 0, 0);
        acc[mt][1] = __builtin_amdgcn_mfma_f32_16x16x32_f16(afr, bfr[1], acc[mt][1], 0, 0, 0);
      }
    }
  }

  const bool isA = (n0 < HDIM);
  float* dst = isA ? out_a : out_z;
  const int cb = isA ? n0 : (n0 - HDIM);
#pragma unroll
  for (int mt = 0; mt < 8; ++mt)
#pragma unroll
    for (int nt = 0; nt < 2; ++nt) {
      const int col = cb + wv * 32 + nt * 16 + c;
#pragma unroll
      for (int i = 0; i < 4; ++i) {
        const int row = m0 + mt * 16 + hi * 4 + i;
        dst[(size_t)row * HDIM + col] = (acc[mt][nt][i] - mng[nt]) * invg[nt] + btg[nt];
      }
    }
}

// ---------------- Phase 2: r7 structure, batch spread ACROSS XCDs ----------------
// SINGLE CHANGE vs r7 (best reproducible, 2595us): block mapping.
//   r3-r9: bid = g*16+b  -> a batch's 8 blocks all had bid%8 == b%8 -> ONE XCD.
//          All 8 blocks' poll sweeps (64 lines each, continuous) + publish
//          fan-out funneled through a single XCD<->fabric port.
//   now:   g = bid&7, b = bid>>3 -> batch b's blocks = bids 8b..8b+7 -> one per
//          XCD (round-robin heuristic) -> 8 parallel fabric paths for polls.
// Everything else byte-identical to r7: 3-slot ring + tail-issued carried
// prefetch, 2 interleaved MFMA chains, gbuf+bar2, expf, out-store-then-publish,
// {tag,f32} packed relaxed agent-scope atoms, equality spin (protocol r3).
__global__ __launch_bounds__(512, 2) void rnn_sync_kernel(
    const float* __restrict__ U,
    float* __restrict__ out,              // [16][2000][512]: w_a in, h out (in place)
    const float* __restrict__ wz,         // [16][2000][512]
    u64* __restrict__ xbuf)               // [2][16][512] {tag,val} -- memset 0 per launch
{
  __shared__ __align__(16) _Float16 hbuf[512];
  __shared__ float hf32[512];
  __shared__ float gbuf[128];
  __shared__ float waring[8][64];
  __shared__ float wzring[8][64];

  const int tid  = threadIdx.x;
  const int w    = tid >> 6;
  const int lane = tid & 63;
  const int c    = lane & 15;
  const int hi   = lane >> 4;
  const int bid  = blockIdx.x;
  const int g    = bid & 7, b = bid >> 3;   // <<< THE CHANGE (was b=bid&15, g=bid>>4)
  const int g0   = g * 64;
  const size_t obase = (size_t)b * TSTEPS * HDIM;

  // persistent U B-fragments: wave w owns local gate cols [w*16, w*16+16)
  const int L    = w * 16 + c;
  const int urow = (L < 64) ? (g0 + L) : (HDIM + g0 + (L - 64));
  f16x8 ufrag[16];
  {
    const float* up = &U[(size_t)urow * HDIM + hi * 8];
#pragma unroll
    for (int kt = 0; kt < 16; ++kt) {
      float4 lo = *(const float4*)&up[kt * 32];
      float4 h4 = *(const float4*)&up[kt * 32 + 4];
      f16x8 f;
      f[0] = (_Float16)lo.x; f[1] = (_Float16)lo.y;
      f[2] = (_Float16)lo.z; f[3] = (_Float16)lo.w;
      f[4] = (_Float16)h4.x; f[5] = (_Float16)h4.y;
      f[6] = (_Float16)h4.z; f[7] = (_Float16)h4.w;
      ufrag[kt] = f;
    }
  }

  hbuf[tid] = (_Float16)0.f;
  hf32[tid] = 0.f;
#pragma unroll
  for (int p = 0; p < 3; ++p) {
    if (tid < 64)        waring[p][tid]      = out[obase + (size_t)p * HDIM + g0 + tid];
    else if (tid < 128)  wzring[p][tid - 64] = wz [obase + (size_t)p * HDIM + g0 + (tid - 64)];
  }
  float pv_carry = 0.f;                      // holds w[t+3] entering iteration t
  if (tid < 64)       pv_carry = out[obase + (size_t)3 * HDIM + g0 + tid];
  else if (tid < 128) pv_carry = wz [obase + (size_t)3 * HDIM + g0 + (tid - 64)];
  __syncthreads();

  for (int t = 0; t < TSTEPS; ++t) {
    // ---- A: acquire h_t -- spin + LDS write ONLY before bar1 ----
    if (t > 0) {
      u64* xb = &xbuf[((size_t)(t & 1) * NBATCH + b) * HDIM];
      u64 v;
      do {
        v = __hip_atomic_load(&xb[tid], __ATOMIC_RELAXED, __HIP_MEMORY_SCOPE_AGENT);
      } while ((unsigned)(v >> 32) != (unsigned)t);
      const float hv = __uint_as_float((unsigned)v);
      hbuf[tid] = (_Float16)hv;
      hf32[tid] = hv;
    }
    __syncthreads();                                   // bar1: hbuf/hf32 ready

    const float hold = (tid < 64) ? hf32[g0 + tid] : 0.f;  // read before bar2

    // ---- B: gates (2 interleaved MFMA chains) ----
    f32x4 acc0 = {0.f, 0.f, 0.f, 0.f};
    f32x4 acc1 = {0.f, 0.f, 0.f, 0.f};
#pragma unroll
    for (int ktg = 0; ktg < 4; ++ktg) {
      f16x8 af[4];
#pragma unroll
      for (int q = 0; q < 4; ++q)
        af[q] = *(const f16x8*)&hbuf[ktg * 128 + q * 32 + hi * 8];
      acc0 = __builtin_amdgcn_mfma_f32_16x16x32_f16(af[0], ufrag[ktg * 4 + 0], acc0, 0, 0, 0);
      acc1 = __builtin_amdgcn_mfma_f32_16x16x32_f16(af[1], ufrag[ktg * 4 + 1], acc1, 0, 0, 0);
      acc0 = __builtin_amdgcn_mfma_f32_16x16x32_f16(af[2], ufrag[ktg * 4 + 2], acc0, 0, 0, 0);
      acc1 = __builtin_amdgcn_mfma_f32_16x16x32_f16(af[3], ufrag[ktg * 4 + 3], acc1, 0, 0, 0);
    }
    if (lane < 16) gbuf[w * 16 + lane] = acc0[0] + acc1[0];
    __syncthreads();                                   // bar2: gbuf ready

    // ---- C: h update + publish (r3 order: out store, then publish) ----
    if (tid < 64) {
      const float a  = gbuf[tid]      + waring[t & 7][tid];
      const float zg = gbuf[64 + tid] + wzring[t & 7][tid];
      const float z  = 1.f / (1.f + expf(-zg));
      const float hc = fmaxf(a, 0.f);
      const float hn = z * hold + (1.f - z) * hc;
      out[obase + (size_t)t * HDIM + g0 + tid] = hn;
      if (t + 1 < TSTEPS) {
        const u64 pkt = ((u64)(unsigned)(t + 1) << 32) | (u64)__float_as_uint(hn);
        __hip_atomic_store(&xbuf[((size_t)((t + 1) & 1) * NBATCH + b) * HDIM + g0 + tid],
                           pkt, __ATOMIC_RELAXED, __HIP_MEMORY_SCOPE_AGENT);
      }
    }

    // ---- D: hidden tail -- ring write (carry from last iter) + NEW issue ----
    if (t + 3 < TSTEPS) {
      if (tid < 64)       waring[(t + 3) & 7][tid]      = pv_carry;
      else if (tid < 128) wzring[(t + 3) & 7][tid - 64] = pv_carry;
    }
    if (t + 4 < TSTEPS) {   // issue w[t+4]; vmcnt-waited a full iteration later
      if (tid < 64)       pv_carry = out[obase + (size_t)(t + 4) * HDIM + g0 + tid];
      else if (tid < 128) pv_carry = wz [obase + (size_t)(t + 4) * HDIM + g0 + (tid - 64)];
    }
  }
}

extern "C" void kernel_launch(void* const* d_in, const int* in_sizes, int n_in,
                              void* d_out, int out_size, void* d_ws, size_t ws_size,
                              hipStream_t stream) {
  const float* x     = (const float*)d_in[0];
  const float* W     = (const float*)d_in[1];
  const float* U     = (const float*)d_in[2];
  const float* gamma = (const float*)d_in[3];
  const float* beta  = (const float*)d_in[4];
  const float* rmean = (const float*)d_in[5];
  const float* rvar  = (const float*)d_in[6];
  float* out = (float*)d_out;

  const size_t wz_bytes = (size_t)MTOT * HDIM * sizeof(float);   // 65,536,000
  float* wzp = (float*)d_ws;
  u64*  xbuf = (u64*)((char*)d_ws + wz_bytes);                   // [2][16][512] u64

  hipMemsetAsync(xbuf, 0, (size_t)2 * NBATCH * HDIM * sizeof(u64), stream);

  dim3 g1(MTOT / 128, (HDIM * 2) / 128), b1(256);
  gemm_bn_f16_kernel<<<g1, b1, 0, stream>>>(x, W, gamma, beta, rmean, rvar, out, wzp);
  rnn_sync_kernel<<<dim3(128), dim3(512), 0, stream>>>(U, out, wzp, xbuf);
}

// Round 12
// 2644.985 us; speedup vs baseline: 1.5842x; 1.0989x over previous
//
#include <hip/hip_runtime.h>

#define TSTEPS 2000
#define NBATCH 16
#define DDIM   512
#define HDIM   512
#define MTOT   (NBATCH * TSTEPS)
#define LEPS   1e-5f

typedef _Float16 f16x8 __attribute__((ext_vector_type(8)));
typedef _Float16 f16x4 __attribute__((ext_vector_type(4)));
typedef float    f32x4 __attribute__((ext_vector_type(4)));
typedef unsigned long long u64;

// ---------------- Phase 1: w = BN(x @ W^T), f16 MFMA ----------------  (r4, verified ~60us)
__global__ __launch_bounds__(256) void gemm_bn_f16_kernel(
    const float* __restrict__ x, const float* __restrict__ W,
    const float* __restrict__ gamma, const float* __restrict__ beta,
    const float* __restrict__ rmean, const float* __restrict__ rvar,
    float* __restrict__ out_a, float* __restrict__ out_z)
{
  __shared__ _Float16 Asm[128 * 64];
  __shared__ _Float16 Bsm[128 * 64];
  const int tid  = threadIdx.x;
  const int wv   = tid >> 6;
  const int lane = tid & 63;
  const int c    = lane & 15;
  const int hi   = lane >> 4;
  const int m0   = blockIdx.x * 128;
  const int n0   = blockIdx.y * 128;

  float invg[2], mng[2], btg[2];
#pragma unroll
  for (int nt = 0; nt < 2; ++nt) {
    const int gc = n0 + wv * 32 + nt * 16 + c;
    invg[nt] = gamma[gc] * rsqrtf(rvar[gc] + LEPS);
    mng[nt]  = rmean[gc];
    btg[nt]  = beta[gc];
  }

  f32x4 acc[8][2];
#pragma unroll
  for (int mt = 0; mt < 8; ++mt)
#pragma unroll
    for (int nt = 0; nt < 2; ++nt) acc[mt][nt] = (f32x4){0.f, 0.f, 0.f, 0.f};

  const int sf4  = tid & 15;
  const int srow = tid >> 4;

  for (int k0 = 0; k0 < DDIM; k0 += 64) {
    __syncthreads();
#pragma unroll
    for (int p = 0; p < 8; ++p) {
      const int r = p * 16 + srow;
      float4 va = *(const float4*)&x[(size_t)(m0 + r) * DDIM + k0 + sf4 * 4];
      float4 vb = *(const float4*)&W[(size_t)(n0 + r) * DDIM + k0 + sf4 * 4];
      f16x4 ha, hb;
      ha[0] = (_Float16)va.x; ha[1] = (_Float16)va.y;
      ha[2] = (_Float16)va.z; ha[3] = (_Float16)va.w;
      hb[0] = (_Float16)vb.x; hb[1] = (_Float16)vb.y;
      hb[2] = (_Float16)vb.z; hb[3] = (_Float16)vb.w;
      const int byo = r * 128 + ((sf4 * 8) ^ ((r & 7) << 4));
      *(f16x4*)((char*)Asm + byo) = ha;
      *(f16x4*)((char*)Bsm + byo) = hb;
    }
    __syncthreads();
#pragma unroll
    for (int kc = 0; kc < 2; ++kc) {
      const int kof = (kc * 32 + hi * 8) * 2;
      f16x8 bfr[2];
#pragma unroll
      for (int nt = 0; nt < 2; ++nt) {
        const int rr = wv * 32 + nt * 16 + c;
        bfr[nt] = *(const f16x8*)((const char*)Bsm + rr * 128 + (kof ^ ((rr & 7) << 4)));
      }
#pragma unroll
      for (int mt = 0; mt < 8; ++mt) {
        const int rr = mt * 16 + c;
        f16x8 afr = *(const f16x8*)((const char*)Asm + rr * 128 + (kof ^ ((rr & 7) << 4)));
        acc[mt][0] = __builtin_amdgcn_mfma_f32_16x16x32_f16(afr, bfr[0], acc[mt][0], 0, 0, 0);
        acc[mt][1] = __builtin_amdgcn_mfma_f32_16x16x32_f16(afr, bfr[1], acc[mt][1], 0, 0, 0);
      }
    }
  }

  const bool isA = (n0 < HDIM);
  float* dst = isA ? out_a : out_z;
  const int cb = isA ? n0 : (n0 - HDIM);
#pragma unroll
  for (int mt = 0; mt < 8; ++mt)
#pragma unroll
    for (int nt = 0; nt < 2; ++nt) {
      const int col = cb + wv * 32 + nt * 16 + c;
#pragma unroll
      for (int i = 0; i < 4; ++i) {
        const int row = m0 + mt * 16 + hi * 4 + i;
        dst[(size_t)row * HDIM + col] = (acc[mt][nt][i] - mng[nt]) * invg[nt] + btg[nt];
      }
    }
}

// ---------------- Phase 2: champion r7 configuration (communication floor) ----------
// 128 blocks = 16 batches x 8 groups, CONGRUENT mapping bid = g*16+b (a batch's
// 8 blocks share bid%8 -> same-XCD heuristic; r11 proved the spread mapping is
// strictly worse: FETCH 170->579MB, dur +9%). Protocol: {tag,f32 h} packed
// 8-byte relaxed agent-scope atoms, equality spin on parity slots, fence-free
// (r3 safety argument). Per step: spin+LDS write | bar1 | 2 interleaved MFMA
// chains -> gbuf | bar2 | wave-0 gate math, out-store, publish | hidden tail
// (ring write from carried prefetch + issue w[t+4]).
// Floor accounting (r4-r11 falsification ladder): per-step ~3120cy =
// agent-scope store->load visibility + poll quantization (~2100cy, MALL-class,
// irreducible at source level) + compute chain (~1000cy, overlapped -- all
// chain micro-variants measured null).
__global__ __launch_bounds__(512, 2) void rnn_sync_kernel(
    const float* __restrict__ U,
    float* __restrict__ out,              // [16][2000][512]: w_a in, h out (in place)
    const float* __restrict__ wz,         // [16][2000][512]
    u64* __restrict__ xbuf)               // [2][16][512] {tag,val} -- memset 0 per launch
{
  __shared__ __align__(16) _Float16 hbuf[512];
  __shared__ float hf32[512];
  __shared__ float gbuf[128];
  __shared__ float waring[8][64];
  __shared__ float wzring[8][64];

  const int tid  = threadIdx.x;
  const int w    = tid >> 6;
  const int lane = tid & 63;
  const int c    = lane & 15;
  const int hi   = lane >> 4;
  const int bid  = blockIdx.x;
  const int b    = bid & 15, g = bid >> 4;   // congruent mapping (champion)
  const int g0   = g * 64;
  const size_t obase = (size_t)b * TSTEPS * HDIM;

  // persistent U B-fragments: wave w owns local gate cols [w*16, w*16+16)
  const int L    = w * 16 + c;
  const int urow = (L < 64) ? (g0 + L) : (HDIM + g0 + (L - 64));
  f16x8 ufrag[16];
  {
    const float* up = &U[(size_t)urow * HDIM + hi * 8];
#pragma unroll
    for (int kt = 0; kt < 16; ++kt) {
      float4 lo = *(const float4*)&up[kt * 32];
      float4 h4 = *(const float4*)&up[kt * 32 + 4];
      f16x8 f;
      f[0] = (_Float16)lo.x; f[1] = (_Float16)lo.y;
      f[2] = (_Float16)lo.z; f[3] = (_Float16)lo.w;
      f[4] = (_Float16)h4.x; f[5] = (_Float16)h4.y;
      f[6] = (_Float16)h4.z; f[7] = (_Float16)h4.w;
      ufrag[kt] = f;
    }
  }

  hbuf[tid] = (_Float16)0.f;
  hf32[tid] = 0.f;
#pragma unroll
  for (int p = 0; p < 3; ++p) {
    if (tid < 64)        waring[p][tid]      = out[obase + (size_t)p * HDIM + g0 + tid];
    else if (tid < 128)  wzring[p][tid - 64] = wz [obase + (size_t)p * HDIM + g0 + (tid - 64)];
  }
  float pv_carry = 0.f;                      // holds w[t+3] entering iteration t
  if (tid < 64)       pv_carry = out[obase + (size_t)3 * HDIM + g0 + tid];
  else if (tid < 128) pv_carry = wz [obase + (size_t)3 * HDIM + g0 + (tid - 64)];
  __syncthreads();

  for (int t = 0; t < TSTEPS; ++t) {
    // ---- A: acquire h_t -- spin + LDS write ONLY before bar1 ----
    if (t > 0) {
      u64* xb = &xbuf[((size_t)(t & 1) * NBATCH + b) * HDIM];
      u64 v;
      do {
        v = __hip_atomic_load(&xb[tid], __ATOMIC_RELAXED, __HIP_MEMORY_SCOPE_AGENT);
      } while ((unsigned)(v >> 32) != (unsigned)t);
      const float hv = __uint_as_float((unsigned)v);
      hbuf[tid] = (_Float16)hv;
      hf32[tid] = hv;
    }
    __syncthreads();                                   // bar1: hbuf/hf32 ready

    const float hold = (tid < 64) ? hf32[g0 + tid] : 0.f;  // read before bar2

    // ---- B: gates (2 interleaved MFMA chains) ----
    f32x4 acc0 = {0.f, 0.f, 0.f, 0.f};
    f32x4 acc1 = {0.f, 0.f, 0.f, 0.f};
#pragma unroll
    for (int ktg = 0; ktg < 4; ++ktg) {
      f16x8 af[4];
#pragma unroll
      for (int q = 0; q < 4; ++q)
        af[q] = *(const f16x8*)&hbuf[ktg * 128 + q * 32 + hi * 8];
      acc0 = __builtin_amdgcn_mfma_f32_16x16x32_f16(af[0], ufrag[ktg * 4 + 0], acc0, 0, 0, 0);
      acc1 = __builtin_amdgcn_mfma_f32_16x16x32_f16(af[1], ufrag[ktg * 4 + 1], acc1, 0, 0, 0);
      acc0 = __builtin_amdgcn_mfma_f32_16x16x32_f16(af[2], ufrag[ktg * 4 + 2], acc0, 0, 0, 0);
      acc1 = __builtin_amdgcn_mfma_f32_16x16x32_f16(af[3], ufrag[ktg * 4 + 3], acc1, 0, 0, 0);
    }
    if (lane < 16) gbuf[w * 16 + lane] = acc0[0] + acc1[0];
    __syncthreads();                                   // bar2: gbuf ready

    // ---- C: h update + publish (out store, then publish) ----
    if (tid < 64) {
      const float a  = gbuf[tid]      + waring[t & 7][tid];
      const float zg = gbuf[64 + tid] + wzring[t & 7][tid];
      const float z  = 1.f / (1.f + expf(-zg));
      const float hc = fmaxf(a, 0.f);
      const float hn = z * hold + (1.f - z) * hc;
      out[obase + (size_t)t * HDIM + g0 + tid] = hn;
      if (t + 1 < TSTEPS) {
        const u64 pkt = ((u64)(unsigned)(t + 1) << 32) | (u64)__float_as_uint(hn);
        __hip_atomic_store(&xbuf[((size_t)((t + 1) & 1) * NBATCH + b) * HDIM + g0 + tid],
                           pkt, __ATOMIC_RELAXED, __HIP_MEMORY_SCOPE_AGENT);
      }
    }

    // ---- D: hidden tail -- ring write (carry from last iter) + NEW issue ----
    if (t + 3 < TSTEPS) {
      if (tid < 64)       waring[(t + 3) & 7][tid]      = pv_carry;
      else if (tid < 128) wzring[(t + 3) & 7][tid - 64] = pv_carry;
    }
    if (t + 4 < TSTEPS) {   // issue w[t+4]; vmcnt-waited a full iteration later
      if (tid < 64)       pv_carry = out[obase + (size_t)(t + 4) * HDIM + g0 + tid];
      else if (tid < 128) pv_carry = wz [obase + (size_t)(t + 4) * HDIM + g0 + (tid - 64)];
    }
  }
}

extern "C" void kernel_launch(void* const* d_in, const int* in_sizes, int n_in,
                              void* d_out, int out_size, void* d_ws, size_t ws_size,
                              hipStream_t stream) {
  const float* x     = (const float*)d_in[0];
  const float* W     = (const float*)d_in[1];
  const float* U     = (const float*)d_in[2];
  const float* gamma = (const float*)d_in[3];
  const float* beta  = (const float*)d_in[4];
  const float* rmean = (const float*)d_in[5];
  const float* rvar  = (const float*)d_in[6];
  float* out = (float*)d_out;

  const size_t wz_bytes = (size_t)MTOT * HDIM * sizeof(float);   // 65,536,000
  float* wzp = (float*)d_ws;
  u64*  xbuf = (u64*)((char*)d_ws + wz_bytes);                   // [2][16][512] u64

  hipMemsetAsync(xbuf, 0, (size_t)2 * NBATCH * HDIM * sizeof(u64), stream);

  dim3 g1(MTOT / 128, (HDIM * 2) / 128), b1(256);
  gemm_bn_f16_kernel<<<g1, b1, 0, stream>>>(x, W, gamma, beta, rmean, rvar, out, wzp);
  rnn_sync_kernel<<<dim3(128), dim3(512), 0, stream>>>(U, out, wzp, xbuf);
}